// Round 9
// baseline (256.831 us; speedup 1.0000x reference)
//
#include <hip/hip_runtime.h>
#include <hip/hip_bf16.h>
#include <math.h>

#define NEGV (-1000000000.0f)
constexpr int Bb = 8, Ll = 4096, Hh = 512, Cc = 64, Aa = 512;

typedef float f32x4 __attribute__((ext_vector_type(4)));
typedef short s16x8 __attribute__((ext_vector_type(8)));

__device__ inline ushort f2bf(float f) {
  union { float f; uint u; } v; v.f = f;
  uint u = v.u;
  return (ushort)((u + 0x7FFFu + ((u >> 16) & 1u)) >> 16);
}

// async global->LDS, 16B per lane. LDS ptr must be wave-uniform.
__device__ __forceinline__ void gl16(const void* g, void* l) {
  __builtin_amdgcn_global_load_lds(
      reinterpret_cast<const __attribute__((address_space(1))) unsigned int*>(
          reinterpret_cast<uintptr_t>(g)),
      reinterpret_cast<__attribute__((address_space(3))) unsigned int*>(
          reinterpret_cast<uintptr_t>(l)),
      16, 0, 0);
}

// ---------------------------------------------------------------------------
// k_front: 6 block-uniform roles in ONE dispatch:
//   [0,2048)     cvtT:  hidb[l][h], hidbT[b][h][l] = bf16(hid) (64l x 128h
//                tiles; float4 loads, uint2/uint4 stores)
//   [2048,2112)  kT_pw: pwT[a][k] = bf16(pw[k][a])
//   [2112,2240)  init:  logits[b][l] = sb + log1p(max(cnt,0))
//   [2240,2248)  cmax:  cmax[b] = max_l cnt[b][l]
//   [2248,2760)  k2:    actT[b][c][l] = relu(act), dinv = 1/max(rowsum,1)
//   [2760,2824)  zero:  cctx = 0 (accumulated by k5 atomics)
// ---------------------------------------------------------------------------
__global__ __launch_bounds__(256) void k_front(
    const float* __restrict__ hid, const int* __restrict__ cnt,
    const float* __restrict__ sb, const float* __restrict__ pw,
    const float* __restrict__ act, ushort* __restrict__ hidb,
    ushort* __restrict__ hidbT, float* __restrict__ logits,
    ushort* __restrict__ pwT, int* __restrict__ cmax,
    float* __restrict__ actT, float* __restrict__ dinv,
    float* __restrict__ cctx) {
  __shared__ float shf[64 * 68];  // 17.4 KB, aliased per role
  ushort* sh = (ushort*)shf;
  const int bid = blockIdx.x;
  const int tid = threadIdx.x;

  if (bid < 2048) {  // ---- cvtT: 64l x 128h tile ----
    const int b = bid >> 8;
    const int rem = bid & 255;
    const int h0 = (rem >> 6) * 128;
    const int l0 = (rem & 63) * 64;
    const int rr = tid >> 5;         // 0..7
    const int hc4 = (tid & 31) * 4;  // 0..124
#pragma unroll
    for (int i = 0; i < 8; ++i) {
      int r = rr + i * 8;
      float4 f =
          *(const float4*)(hid + ((size_t)(b * Ll + l0 + r)) * Hh + h0 + hc4);
      uint u0 = (uint)f2bf(f.x) | ((uint)f2bf(f.y) << 16);
      uint u1 = (uint)f2bf(f.z) | ((uint)f2bf(f.w) << 16);
      *(uint2*)(hidb + ((size_t)(b * Ll + l0 + r)) * Hh + h0 + hc4) =
          make_uint2(u0, u1);
      *(uint2*)(sh + r * 132 + hc4) = make_uint2(u0, u1);
    }
    __syncthreads();
    const int ht = tid >> 1;         // 0..127
    const int d0 = (tid & 1) * 16;   // dword group; dword p holds l=2p,2p+1
    uint v[16];
#pragma unroll
    for (int k = 0; k < 16; ++k) {
      int p = d0 + k;
      v[k] = (uint)sh[(2 * p) * 132 + ht] | ((uint)sh[(2 * p + 1) * 132 + ht] << 16);
    }
    ushort* dst = hidbT + ((size_t)(b * Hh + h0 + ht)) * Ll + l0 + 2 * d0;
    *(uint4*)(dst + 0) = (uint4){v[0], v[1], v[2], v[3]};
    *(uint4*)(dst + 8) = (uint4){v[4], v[5], v[6], v[7]};
    *(uint4*)(dst + 16) = (uint4){v[8], v[9], v[10], v[11]};
    *(uint4*)(dst + 24) = (uint4){v[12], v[13], v[14], v[15]};
  } else if (bid < 2112) {  // ---- kT_pw ----
    const int bx = bid - 2048;
    const int k0 = (bx >> 3) * 64, a0 = (bx & 7) * 64;
#pragma unroll
    for (int i = 0; i < 16; ++i) {
      int e = tid + i * 256;
      int kk = e >> 6, aa = e & 63;
      sh[aa * 65 + kk] = f2bf(pw[(size_t)(k0 + kk) * Aa + a0 + aa]);
    }
    __syncthreads();
#pragma unroll
    for (int i = 0; i < 16; ++i) {
      int e = tid + i * 256;
      int aa = e >> 6, kk = e & 63;
      pwT[(size_t)(a0 + aa) * Hh + k0 + kk] = sh[aa * 65 + kk];
    }
  } else if (bid < 2240) {  // ---- logits init ----
    int i = (bid - 2112) * 256 + tid;  // 0..32767
    logits[i] = sb[0] + log1pf(fmaxf((float)cnt[i], 0.f));
  } else if (bid < 2248) {  // ---- cmax: one block per b ----
    int* shi = (int*)shf;
    const int b = bid - 2240;
    const int* p = cnt + b * Ll;
    int m = 0;
#pragma unroll
    for (int j = 0; j < 16; ++j) m = max(m, p[tid + j * 256]);
#pragma unroll
    for (int s = 32; s; s >>= 1) m = max(m, __shfl_xor(m, s));
    if ((tid & 63) == 0) shi[tid >> 6] = m;
    __syncthreads();
    if (tid == 0) cmax[b] = max(max(shi[0], shi[1]), max(shi[2], shi[3]));
  } else if (bid < 2760) {  // ---- k2: relu-transpose + dinv ----
    const int bx = bid - 2248;
    const int b = bx >> 6;
    const int l0 = (bx & 63) * 64;
    const int rr = tid >> 4;         // 0..15
    const int c4 = (tid & 15) * 4;   // 0..60
#pragma unroll
    for (int i = 0; i < 4; ++i) {
      int r = rr + i * 16;
      float4 a4 =
          *(const float4*)(act + ((size_t)(b * Ll + l0 + r)) * Cc + c4);
      a4.x = fmaxf(a4.x, 0.f);
      a4.y = fmaxf(a4.y, 0.f);
      a4.z = fmaxf(a4.z, 0.f);
      a4.w = fmaxf(a4.w, 0.f);
      *(float4*)(shf + r * 68 + c4) = a4;
    }
    __syncthreads();
    if (tid < 64) {
      float s = 0.f;
#pragma unroll 8
      for (int c = 0; c < 64; ++c) s += shf[tid * 68 + c];
      dinv[b * Ll + l0 + tid] = 1.0f / fmaxf(s, 1.0f);
    }
    const int c = tid >> 2;
    const int l16 = (tid & 3) * 16;
    float v[16];
#pragma unroll
    for (int q = 0; q < 16; ++q) v[q] = shf[(l16 + q) * 68 + c];
    float* dst = actT + ((size_t)(b * Cc + c)) * Ll + l0 + l16;
#pragma unroll
    for (int j = 0; j < 4; ++j)
      *(float4*)(dst + 4 * j) = make_float4(v[4 * j], v[4 * j + 1],
                                            v[4 * j + 2], v[4 * j + 3]);
  } else {  // ---- zero cctx ----
    const int bz = bid - 2760;
    float* p = cctx + ((size_t)(bz * 256 + tid)) * 16;
    f32x4 z = (f32x4){0.f, 0.f, 0.f, 0.f};
    *(f32x4*)(p + 0) = z;
    *(f32x4*)(p + 4) = z;
    *(f32x4*)(p + 8) = z;
    *(f32x4*)(p + 12) = z;
  }
}

// ---------------------------------------------------------------------------
// k0_gemm: logits += sum_a tanh((hid @ pw)[m][a] + pb[a]) * sw[a]
// Pure-bf16 MFMA 16x16x32, 128x128 tile, BK=32, double-buffered LDS filled by
// global_load_lds_dwordx4 (m97 structure).
// ---------------------------------------------------------------------------
__global__ __launch_bounds__(256) void k0_gemm(
    const ushort* __restrict__ hidb, const ushort* __restrict__ pwT,
    const float* __restrict__ pb, const float* __restrict__ sw,
    float* __restrict__ logits) {
  __shared__ ushort smem[16384];
  const int bm = blockIdx.x, bn = blockIdx.y;
  const int tid = threadIdx.x;
  const int lane = tid & 63;
  const int w = tid >> 6;
  const int wm = w >> 1, wn = w & 1;
  const int lc = lane & 15, lq = lane >> 4;

  const int srow = tid >> 2;
  const int schunk = (tid & 3) * 8;
  const ushort* Ag = hidb + ((size_t)(bm * 128 + srow)) * Hh + schunk;
  const ushort* Bg = pwT + ((size_t)(bn * 128 + srow)) * Hh + schunk;
  const int wrow = 16 * w;

  f32x4 acc[4][4];
#pragma unroll
  for (int mi = 0; mi < 4; ++mi)
#pragma unroll
    for (int ni = 0; ni < 4; ++ni) acc[mi][ni] = (f32x4){0.f, 0.f, 0.f, 0.f};

  const int aoffc = (wm * 64 + lc) * 32 + lq * 8;
  const int boffc = (wn * 64 + lc) * 32 + lq * 8;

#define K0_STAGE(buf, kb)                                   \
  do {                                                      \
    const ushort* ag = Ag + (kb) * 32;                      \
    const ushort* bg = Bg + (kb) * 32;                      \
    ushort* la = smem + (buf) * 4096 + wrow * 32;           \
    ushort* lb = smem + 8192 + (buf) * 4096 + wrow * 32;    \
    gl16(ag, la);                                           \
    gl16(ag + 64 * Hh, la + 64 * 32);                       \
    gl16(bg, lb);                                           \
    gl16(bg + 64 * Hh, lb + 64 * 32);                       \
  } while (0)

  K0_STAGE(0, 0);
  __syncthreads();

  int buf = 0;
  for (int kb = 0; kb < 16; ++kb) {
    if (kb < 15) K0_STAGE(buf ^ 1, kb + 1);
    const ushort* Ab = smem + buf * 4096;
    const ushort* Bt = smem + 8192 + buf * 4096;
    s16x8 af[4], bfr[4];
#pragma unroll
    for (int mi = 0; mi < 4; ++mi)
      af[mi] = *(const s16x8*)(Ab + aoffc + mi * 512);
#pragma unroll
    for (int ni = 0; ni < 4; ++ni)
      bfr[ni] = *(const s16x8*)(Bt + boffc + ni * 512);
#pragma unroll
    for (int mi = 0; mi < 4; ++mi)
#pragma unroll
      for (int ni = 0; ni < 4; ++ni)
        acc[mi][ni] = __builtin_amdgcn_mfma_f32_16x16x32_bf16(
            af[mi], bfr[ni], acc[mi][ni], 0, 0, 0);
    __syncthreads();
    buf ^= 1;
  }
#undef K0_STAGE

  float pbv[4], swv[4];
#pragma unroll
  for (int ni = 0; ni < 4; ++ni) {
    int n = bn * 128 + wn * 64 + ni * 16 + lc;
    pbv[ni] = pb[n];
    swv[ni] = sw[n];
  }
#pragma unroll
  for (int mi = 0; mi < 4; ++mi) {
#pragma unroll
    for (int r = 0; r < 4; ++r) {
      float s = 0.f;
#pragma unroll
      for (int ni = 0; ni < 4; ++ni) {
        float x = acc[mi][ni][r] + pbv[ni];
        float e = __expf(2.f * x);
        float th = 1.f - 2.f / (e + 1.f);
        s = fmaf(th, swv[ni], s);
      }
      s += __shfl_xor(s, 1);
      s += __shfl_xor(s, 2);
      s += __shfl_xor(s, 4);
      s += __shfl_xor(s, 8);
      if (lc == 0) {
        int m = bm * 128 + wm * 64 + mi * 16 + lq * 4 + r;
        atomicAdd(&logits[m], s);
      }
    }
  }
}

// ---------------------------------------------------------------------------
// K3: per (b,c) row softmax over L -> weights output (fp32) + bf16 copy.
// ---------------------------------------------------------------------------
__global__ void k3_softmax(const float* __restrict__ actT,
                           const float* __restrict__ logits,
                           float* __restrict__ wout,
                           ushort* __restrict__ wb16,
                           int* __restrict__ hasany) {
  __shared__ float rmax[4], rcnt[4], rsum[4];
  const int bid = blockIdx.x;  // b*64+c
  const int b = bid >> 6;
  const int tid = threadIdx.x;
  const float* arow = actT + (size_t)bid * Ll;

  float xs[16];
  float lmax = NEGV, fcnt = 0.f;
#pragma unroll
  for (int i = 0; i < 16; ++i) {
    int l = tid + i * 256;
    float a = arow[l];
    float x;
    if (a > 0.f) {
      x = logits[b * Ll + l] + log1pf(a);
      fcnt += 1.f;
    } else {
      x = NEGV;
    }
    xs[i] = x;
    lmax = fmaxf(lmax, x);
  }
#pragma unroll
  for (int m = 32; m >= 1; m >>= 1) {
    lmax = fmaxf(lmax, __shfl_xor(lmax, m));
    fcnt += __shfl_xor(fcnt, m);
  }
  if ((tid & 63) == 0) { rmax[tid >> 6] = lmax; rcnt[tid >> 6] = fcnt; }
  __syncthreads();
  float m4 = fmaxf(fmaxf(rmax[0], rmax[1]), fmaxf(rmax[2], rmax[3]));
  float call = rcnt[0] + rcnt[1] + rcnt[2] + rcnt[3];

  float lsum = 0.f;
#pragma unroll
  for (int i = 0; i < 16; ++i) {
    float e = expf(xs[i] - m4);
    xs[i] = e;
    lsum += e;
  }
#pragma unroll
  for (int m = 32; m >= 1; m >>= 1) lsum += __shfl_xor(lsum, m);
  if ((tid & 63) == 0) rsum[tid >> 6] = lsum;
  __syncthreads();
  float s = rsum[0] + rsum[1] + rsum[2] + rsum[3];
  int any = call > 0.5f;
  float inv = any ? 1.0f / s : 0.f;
#pragma unroll
  for (int i = 0; i < 16; ++i) {
    float wv = xs[i] * inv;
    wout[(size_t)bid * Ll + tid + i * 256] = wv;
    wb16[(size_t)bid * Ll + tid + i * 256] = f2bf(wv);
  }
  if (tid == 0) hasany[bid] = any;
}

// ---------------------------------------------------------------------------
// K5: bf16 MFMA partial GEMM, atomically accumulated into cctx (zeroed by
// k_front). 2-deep register pipeline over 8 k-steps.
// ---------------------------------------------------------------------------
__global__ __launch_bounds__(256) void k5_mfma(
    const ushort* __restrict__ wb16, const ushort* __restrict__ hidbT,
    float* __restrict__ cctx) {
  const int b = blockIdx.x, nt = blockIdx.y, kz = blockIdx.z;  // kz 0..15
  const int tid = threadIdx.x;
  const int w = tid >> 6, lane = tid & 63;
  const int lc = lane & 15, lq = lane >> 4;
  const int h0 = nt * 128 + w * 32;

  f32x4 acc[4][2];
#pragma unroll
  for (int mi = 0; mi < 4; ++mi)
#pragma unroll
    for (int ni = 0; ni < 2; ++ni) acc[mi][ni] = (f32x4){0.f, 0.f, 0.f, 0.f};

  const ushort* Abase =
      wb16 + (size_t)b * Cc * Ll + (size_t)lc * Ll + kz * 256 + lq * 8;
  const ushort* Bbase =
      hidbT + ((size_t)(b * Hh + h0 + lc)) * Ll + kz * 256 + lq * 8;

#define K5_LOAD(kb, A, Bv)                                                 \
  do {                                                                     \
    _Pragma("unroll") for (int mi = 0; mi < 4; ++mi) A[mi] =               \
        *(const s16x8*)(Abase + (size_t)mi * 16 * Ll + (kb) * 32);         \
    _Pragma("unroll") for (int ni = 0; ni < 2; ++ni) Bv[ni] =              \
        *(const s16x8*)(Bbase + (size_t)ni * 16 * Ll + (kb) * 32);         \
  } while (0)

#define K5_MFMA(A, Bv)                                                     \
  do {                                                                     \
    _Pragma("unroll") for (int mi = 0; mi < 4; ++mi)                       \
        _Pragma("unroll") for (int ni = 0; ni < 2; ++ni) acc[mi][ni] =     \
            __builtin_amdgcn_mfma_f32_16x16x32_bf16(A[mi], Bv[ni],         \
                                                    acc[mi][ni], 0, 0, 0); \
  } while (0)

  s16x8 aF[4], bF[2], aG[4], bG[2];
  K5_LOAD(0, aF, bF);
  K5_LOAD(1, aG, bG);
  K5_MFMA(aF, bF);
  K5_LOAD(2, aF, bF);
  K5_MFMA(aG, bG);
  K5_LOAD(3, aG, bG);
  K5_MFMA(aF, bF);
  K5_LOAD(4, aF, bF);
  K5_MFMA(aG, bG);
  K5_LOAD(5, aG, bG);
  K5_MFMA(aF, bF);
  K5_LOAD(6, aF, bF);
  K5_MFMA(aG, bG);
  K5_LOAD(7, aG, bG);
  K5_MFMA(aF, bF);
  K5_MFMA(aG, bG);
#undef K5_LOAD
#undef K5_MFMA

#pragma unroll
  for (int mi = 0; mi < 4; ++mi)
#pragma unroll
    for (int ni = 0; ni < 2; ++ni)
#pragma unroll
      for (int r = 0; r < 4; ++r)
        atomicAdd(&cctx[((size_t)(b * Cc + mi * 16 + lq * 4 + r)) * Hh + h0 +
                        ni * 16 + lc],
                  acc[mi][ni][r]);
}

// ---------------------------------------------------------------------------
// K7: attended = mask ? (mix @ cctx) * gate : hidden
// LDS-resident outer product; fallback (!hasany) patched into the LDS copy.
// ---------------------------------------------------------------------------
__global__ __launch_bounds__(256) void k7_out(
    const float* __restrict__ hid, const float* __restrict__ act,
    const float* __restrict__ dinv, const float* __restrict__ cctx,
    const int* __restrict__ hasany, const int* __restrict__ mask,
    const int* __restrict__ cnt, const int* __restrict__ cmax,
    float* __restrict__ out) {
  __shared__ float cct[64][128];   // [c][h] 32 KB
  __shared__ float mixs[64][64];   // [tok][c] 16 KB
  __shared__ float gateb[64];
  __shared__ int maskb[64];
  const int b = blockIdx.x;
  const int l0 = blockIdx.y * 64;
  const int h0 = blockIdx.z * 128;
  const int tid = threadIdx.x;
  const int w = tid >> 6;

  {
    const float* g = cctx + (size_t)(b * Cc + (tid >> 5)) * Hh + h0 + (tid & 31) * 4;
    float* lb = &cct[0][0] + (2 * w) * 128;
#pragma unroll
    for (int i = 0; i < 8; ++i)
      gl16(g + (size_t)(i * 8) * Hh, lb + i * 8 * 128);
  }
#pragma unroll
  for (int i = 0; i < 4; ++i) {
    int e = tid + i * 256;
    int t = e >> 4, c4 = (e & 15) * 4;
    float4 a4 = *(const float4*)(act + ((size_t)(b * Ll + l0 + t)) * Cc + c4);
    float dv = dinv[b * Ll + l0 + t];
    a4.x = fmaxf(a4.x, 0.f) * dv;
    a4.y = fmaxf(a4.y, 0.f) * dv;
    a4.z = fmaxf(a4.z, 0.f) * dv;
    a4.w = fmaxf(a4.w, 0.f) * dv;
    *(float4*)&mixs[t][c4] = a4;
  }
  if (tid < 64) {
    int l = l0 + tid;
    maskb[tid] = mask[b * Ll + l];
    gateb[tid] = 1.0f + (float)cnt[b * Ll + l] / fmaxf((float)cmax[b], 1.0f);
  }
  __syncthreads();

  // fallback patch: rows with no active channel get hid[b][L-1][h]
  {
    int c = tid >> 2, hq = (tid & 3) * 32;
    if (!hasany[b * Cc + c]) {
      const float* hl = hid + ((size_t)(b * Ll + Ll - 1)) * Hh + h0 + hq;
#pragma unroll 8
      for (int j = 0; j < 32; ++j) cct[c][hq + j] = hl[j];
    }
  }
  __syncthreads();

  const int hcol = (tid & 31) * 4;
  const int tok0 = (tid >> 5) * 8;

  f32x4 acc[8];
#pragma unroll
  for (int t = 0; t < 8; ++t) acc[t] = (f32x4){0.f, 0.f, 0.f, 0.f};

#pragma unroll 4
  for (int c0 = 0; c0 < 64; c0 += 4) {
    f32x4 cv0 = *(const f32x4*)&cct[c0 + 0][hcol];
    f32x4 cv1 = *(const f32x4*)&cct[c0 + 1][hcol];
    f32x4 cv2 = *(const f32x4*)&cct[c0 + 2][hcol];
    f32x4 cv3 = *(const f32x4*)&cct[c0 + 3][hcol];
#pragma unroll
    for (int t = 0; t < 8; ++t) {
      f32x4 mv = *(const f32x4*)&mixs[tok0 + t][c0];
      f32x4 a = acc[t];
      a = cv0 * mv.x + a;
      a = cv1 * mv.y + a;
      a = cv2 * mv.z + a;
      a = cv3 * mv.w + a;
      acc[t] = a;
    }
  }

#pragma unroll
  for (int t = 0; t < 8; ++t) {
    int tok = tok0 + t;
    size_t off = ((size_t)(b * Ll + l0 + tok)) * Hh + h0 + hcol;
    f32x4 o;
    if (maskb[tok]) {
      o = acc[t] * gateb[tok];
    } else {
      o = *(const f32x4*)(hid + off);
    }
    *(f32x4*)(out + off) = o;
  }
}

// ---------------------------------------------------------------------------
extern "C" void kernel_launch(void* const* d_in, const int* in_sizes, int n_in,
                              void* d_out, int out_size, void* d_ws,
                              size_t ws_size, hipStream_t stream) {
  const float* hid = (const float*)d_in[0];
  const int* mask = (const int*)d_in[1];
  const int* cnt = (const int*)d_in[2];
  const float* act = (const float*)d_in[3];
  const float* pw = (const float*)d_in[4];
  const float* pb = (const float*)d_in[5];
  const float* sw = (const float*)d_in[6];
  const float* sb = (const float*)d_in[7];

  float* out_att = (float*)d_out;                 // (B,L,H)
  float* out_w = out_att + (size_t)Bb * Ll * Hh;  // (B,C,L)

  float* ws = (float*)d_ws;
  float* cctx = ws;                               // 262144 f
  int* cmaxi = (int*)(ws + 262144);               // 8 i
  float* logits = ws + 262152;                    // 32768 f
  float* actT = ws + 294920;                      // 2097152 f
  float* dinv = ws + 2392072;                     // 32768 f
  int* hasany = (int*)(ws + 2424840);             // 512 i
  ushort* pwT = (ushort*)(ws + 2425352);          // 262144 bf16
  ushort* wb16 = (ushort*)(ws + 2556424);         // 2097152 bf16

  // bf16 copies of hid live in the (not-yet-written) out_att region (67 MB):
  //   hidb  = floats [0 .. 8388608)        (33.5 MB, [l][h] row-major)
  //   hidbT = floats [8388608 .. 16777216) (33.5 MB, per-b [h][l])
  // k0/k5 consume them; k7_out overwrites all of out_att at the very end.
  ushort* hidb = (ushort*)out_att;
  ushort* hidbT = (ushort*)(out_att + 8388608);

  // 5 dispatches total.
  k_front<<<2824, 256, 0, stream>>>(hid, cnt, sb, pw, act, hidb, hidbT,
                                    logits, pwT, cmaxi, actT, dinv, cctx);
  k0_gemm<<<dim3(256, 4), 256, 0, stream>>>(hidb, pwT, pb, sw, logits);
  k3_softmax<<<512, 256, 0, stream>>>(actT, logits, out_w, wb16, hasany);
  k5_mfma<<<dim3(8, 4, 16), 256, 0, stream>>>(wb16, hidbT, cctx);
  k7_out<<<dim3(8, 64, 4), 256, 0, stream>>>(hid, act, dinv, cctx, hasany,
                                             mask, cnt, cmaxi, out_att);
}

// Round 10
// 248.581 us; speedup vs baseline: 1.0332x; 1.0332x over previous
//
#include <hip/hip_runtime.h>
#include <hip/hip_bf16.h>
#include <math.h>

#define NEGV (-1000000000.0f)
constexpr int Bb = 8, Ll = 4096, Hh = 512, Cc = 64, Aa = 512;

typedef float f32x4 __attribute__((ext_vector_type(4)));
typedef short s16x8 __attribute__((ext_vector_type(8)));

__device__ inline ushort f2bf(float f) {
  union { float f; uint u; } v; v.f = f;
  uint u = v.u;
  return (ushort)((u + 0x7FFFu + ((u >> 16) & 1u)) >> 16);
}

__device__ inline uint bfpack2u(float x, float y) {
  return (uint)f2bf(x) | ((uint)f2bf(y) << 16);
}

// async global->LDS, 16B per lane. LDS ptr must be wave-uniform.
__device__ __forceinline__ void gl16(const void* g, void* l) {
  __builtin_amdgcn_global_load_lds(
      reinterpret_cast<const __attribute__((address_space(1))) unsigned int*>(
          reinterpret_cast<uintptr_t>(g)),
      reinterpret_cast<__attribute__((address_space(3))) unsigned int*>(
          reinterpret_cast<uintptr_t>(l)),
      16, 0, 0);
}

// ---------------------------------------------------------------------------
// k_front: 6 block-uniform roles in ONE dispatch:
//   [0,2048)     cvt:   hidb[l][h] = bf16(hid) — pure streaming convert
//   [2048,2112)  kT_pw: pwT[a][k] = bf16(pw[k][a])
//   [2112,2240)  init:  logits[b][l] = sb + log1p(max(cnt,0))
//   [2240,2248)  cmax:  cmax[b] = max_l cnt[b][l]
//   [2248,2760)  k2:    actT[b][c][l] = relu(act), dinv = 1/max(rowsum,1)
//   [2760,2824)  zero:  cctx = 0 (accumulated by k5 atomics)
// ---------------------------------------------------------------------------
__global__ __launch_bounds__(256) void k_front(
    const float* __restrict__ hid, const int* __restrict__ cnt,
    const float* __restrict__ sb, const float* __restrict__ pw,
    const float* __restrict__ act, ushort* __restrict__ hidb,
    float* __restrict__ logits, ushort* __restrict__ pwT,
    int* __restrict__ cmax, float* __restrict__ actT,
    float* __restrict__ dinv, float* __restrict__ cctx) {
  __shared__ float shf[64 * 68];  // 17.4 KB, aliased per role
  ushort* sh = (ushort*)shf;
  const int bid = blockIdx.x;
  const int tid = threadIdx.x;

  if (bid < 2048) {  // ---- cvt: streaming fp32 -> bf16, fully coalesced ----
    size_t i = (size_t)bid * 256 + tid;
#pragma unroll
    for (int r = 0; r < 4; ++r, i += 524288) {
      const float4* p = (const float4*)(hid + i * 8);
      float4 x = p[0], y = p[1];
      uint4 u = {bfpack2u(x.x, x.y), bfpack2u(x.z, x.w),
                 bfpack2u(y.x, y.y), bfpack2u(y.z, y.w)};
      *(uint4*)(hidb + i * 8) = u;
    }
  } else if (bid < 2112) {  // ---- kT_pw ----
    const int bx = bid - 2048;
    const int k0 = (bx >> 3) * 64, a0 = (bx & 7) * 64;
#pragma unroll
    for (int i = 0; i < 16; ++i) {
      int e = tid + i * 256;
      int kk = e >> 6, aa = e & 63;
      sh[aa * 65 + kk] = f2bf(pw[(size_t)(k0 + kk) * Aa + a0 + aa]);
    }
    __syncthreads();
#pragma unroll
    for (int i = 0; i < 16; ++i) {
      int e = tid + i * 256;
      int aa = e >> 6, kk = e & 63;
      pwT[(size_t)(a0 + aa) * Hh + k0 + kk] = sh[aa * 65 + kk];
    }
  } else if (bid < 2240) {  // ---- logits init ----
    int i = (bid - 2112) * 256 + tid;  // 0..32767
    logits[i] = sb[0] + log1pf(fmaxf((float)cnt[i], 0.f));
  } else if (bid < 2248) {  // ---- cmax: one block per b ----
    int* shi = (int*)shf;
    const int b = bid - 2240;
    const int* p = cnt + b * Ll;
    int m = 0;
#pragma unroll
    for (int j = 0; j < 16; ++j) m = max(m, p[tid + j * 256]);
#pragma unroll
    for (int s = 32; s; s >>= 1) m = max(m, __shfl_xor(m, s));
    if ((tid & 63) == 0) shi[tid >> 6] = m;
    __syncthreads();
    if (tid == 0) cmax[b] = max(max(shi[0], shi[1]), max(shi[2], shi[3]));
  } else if (bid < 2760) {  // ---- k2: relu-transpose + dinv ----
    const int bx = bid - 2248;
    const int b = bx >> 6;
    const int l0 = (bx & 63) * 64;
    const int rr = tid >> 4;         // 0..15
    const int c4 = (tid & 15) * 4;   // 0..60
#pragma unroll
    for (int i = 0; i < 4; ++i) {
      int r = rr + i * 16;
      float4 a4 =
          *(const float4*)(act + ((size_t)(b * Ll + l0 + r)) * Cc + c4);
      a4.x = fmaxf(a4.x, 0.f);
      a4.y = fmaxf(a4.y, 0.f);
      a4.z = fmaxf(a4.z, 0.f);
      a4.w = fmaxf(a4.w, 0.f);
      *(float4*)(shf + r * 68 + c4) = a4;
    }
    __syncthreads();
    if (tid < 64) {
      float s = 0.f;
#pragma unroll 8
      for (int c = 0; c < 64; ++c) s += shf[tid * 68 + c];
      dinv[b * Ll + l0 + tid] = 1.0f / fmaxf(s, 1.0f);
    }
    const int c = tid >> 2;
    const int l16 = (tid & 3) * 16;
    float v[16];
#pragma unroll
    for (int q = 0; q < 16; ++q) v[q] = shf[(l16 + q) * 68 + c];
    float* dst = actT + ((size_t)(b * Cc + c)) * Ll + l0 + l16;
#pragma unroll
    for (int j = 0; j < 4; ++j)
      *(float4*)(dst + 4 * j) = make_float4(v[4 * j], v[4 * j + 1],
                                            v[4 * j + 2], v[4 * j + 3]);
  } else {  // ---- zero cctx ----
    const int bz = bid - 2760;
    float* p = cctx + ((size_t)(bz * 256 + tid)) * 16;
    f32x4 z = (f32x4){0.f, 0.f, 0.f, 0.f};
    *(f32x4*)(p + 0) = z;
    *(f32x4*)(p + 4) = z;
    *(f32x4*)(p + 8) = z;
    *(f32x4*)(p + 12) = z;
  }
}

// ---------------------------------------------------------------------------
// k0_gemm: logits += sum_a tanh((hid @ pw)[m][a] + pb[a]) * sw[a]
// Pure-bf16 MFMA 16x16x32, 128x128 tile, BK=32, double-buffered LDS filled by
// global_load_lds_dwordx4 (m97 structure).
// ---------------------------------------------------------------------------
__global__ __launch_bounds__(256) void k0_gemm(
    const ushort* __restrict__ hidb, const ushort* __restrict__ pwT,
    const float* __restrict__ pb, const float* __restrict__ sw,
    float* __restrict__ logits) {
  __shared__ ushort smem[16384];
  const int bm = blockIdx.x, bn = blockIdx.y;
  const int tid = threadIdx.x;
  const int lane = tid & 63;
  const int w = tid >> 6;
  const int wm = w >> 1, wn = w & 1;
  const int lc = lane & 15, lq = lane >> 4;

  const int srow = tid >> 2;
  const int schunk = (tid & 3) * 8;
  const ushort* Ag = hidb + ((size_t)(bm * 128 + srow)) * Hh + schunk;
  const ushort* Bg = pwT + ((size_t)(bn * 128 + srow)) * Hh + schunk;
  const int wrow = 16 * w;

  f32x4 acc[4][4];
#pragma unroll
  for (int mi = 0; mi < 4; ++mi)
#pragma unroll
    for (int ni = 0; ni < 4; ++ni) acc[mi][ni] = (f32x4){0.f, 0.f, 0.f, 0.f};

  const int aoffc = (wm * 64 + lc) * 32 + lq * 8;
  const int boffc = (wn * 64 + lc) * 32 + lq * 8;

#define K0_STAGE(buf, kb)                                   \
  do {                                                      \
    const ushort* ag = Ag + (kb) * 32;                      \
    const ushort* bg = Bg + (kb) * 32;                      \
    ushort* la = smem + (buf) * 4096 + wrow * 32;           \
    ushort* lb = smem + 8192 + (buf) * 4096 + wrow * 32;    \
    gl16(ag, la);                                           \
    gl16(ag + 64 * Hh, la + 64 * 32);                       \
    gl16(bg, lb);                                           \
    gl16(bg + 64 * Hh, lb + 64 * 32);                       \
  } while (0)

  K0_STAGE(0, 0);
  __syncthreads();

  int buf = 0;
  for (int kb = 0; kb < 16; ++kb) {
    if (kb < 15) K0_STAGE(buf ^ 1, kb + 1);
    const ushort* Ab = smem + buf * 4096;
    const ushort* Bt = smem + 8192 + buf * 4096;
    s16x8 af[4], bfr[4];
#pragma unroll
    for (int mi = 0; mi < 4; ++mi)
      af[mi] = *(const s16x8*)(Ab + aoffc + mi * 512);
#pragma unroll
    for (int ni = 0; ni < 4; ++ni)
      bfr[ni] = *(const s16x8*)(Bt + boffc + ni * 512);
#pragma unroll
    for (int mi = 0; mi < 4; ++mi)
#pragma unroll
      for (int ni = 0; ni < 4; ++ni)
        acc[mi][ni] = __builtin_amdgcn_mfma_f32_16x16x32_bf16(
            af[mi], bfr[ni], acc[mi][ni], 0, 0, 0);
    __syncthreads();
    buf ^= 1;
  }
#undef K0_STAGE

  float pbv[4], swv[4];
#pragma unroll
  for (int ni = 0; ni < 4; ++ni) {
    int n = bn * 128 + wn * 64 + ni * 16 + lc;
    pbv[ni] = pb[n];
    swv[ni] = sw[n];
  }
#pragma unroll
  for (int mi = 0; mi < 4; ++mi) {
#pragma unroll
    for (int r = 0; r < 4; ++r) {
      float s = 0.f;
#pragma unroll
      for (int ni = 0; ni < 4; ++ni) {
        float x = acc[mi][ni][r] + pbv[ni];
        float e = __expf(2.f * x);
        float th = 1.f - 2.f / (e + 1.f);
        s = fmaf(th, swv[ni], s);
      }
      s += __shfl_xor(s, 1);
      s += __shfl_xor(s, 2);
      s += __shfl_xor(s, 4);
      s += __shfl_xor(s, 8);
      if (lc == 0) {
        int m = bm * 128 + wm * 64 + mi * 16 + lq * 4 + r;
        atomicAdd(&logits[m], s);
      }
    }
  }
}

// ---------------------------------------------------------------------------
// K3: per (b,c) row softmax over L -> weights output (fp32) + bf16 copy.
// ---------------------------------------------------------------------------
__global__ void k3_softmax(const float* __restrict__ actT,
                           const float* __restrict__ logits,
                           float* __restrict__ wout,
                           ushort* __restrict__ wb16,
                           int* __restrict__ hasany) {
  __shared__ float rmax[4], rcnt[4], rsum[4];
  const int bid = blockIdx.x;  // b*64+c
  const int b = bid >> 6;
  const int tid = threadIdx.x;
  const float* arow = actT + (size_t)bid * Ll;

  float xs[16];
  float lmax = NEGV, fcnt = 0.f;
#pragma unroll
  for (int i = 0; i < 16; ++i) {
    int l = tid + i * 256;
    float a = arow[l];
    float x;
    if (a > 0.f) {
      x = logits[b * Ll + l] + log1pf(a);
      fcnt += 1.f;
    } else {
      x = NEGV;
    }
    xs[i] = x;
    lmax = fmaxf(lmax, x);
  }
#pragma unroll
  for (int m = 32; m >= 1; m >>= 1) {
    lmax = fmaxf(lmax, __shfl_xor(lmax, m));
    fcnt += __shfl_xor(fcnt, m);
  }
  if ((tid & 63) == 0) { rmax[tid >> 6] = lmax; rcnt[tid >> 6] = fcnt; }
  __syncthreads();
  float m4 = fmaxf(fmaxf(rmax[0], rmax[1]), fmaxf(rmax[2], rmax[3]));
  float call = rcnt[0] + rcnt[1] + rcnt[2] + rcnt[3];

  float lsum = 0.f;
#pragma unroll
  for (int i = 0; i < 16; ++i) {
    float e = expf(xs[i] - m4);
    xs[i] = e;
    lsum += e;
  }
#pragma unroll
  for (int m = 32; m >= 1; m >>= 1) lsum += __shfl_xor(lsum, m);
  if ((tid & 63) == 0) rsum[tid >> 6] = lsum;
  __syncthreads();
  float s = rsum[0] + rsum[1] + rsum[2] + rsum[3];
  int any = call > 0.5f;
  float inv = any ? 1.0f / s : 0.f;
#pragma unroll
  for (int i = 0; i < 16; ++i) {
    float wv = xs[i] * inv;
    wout[(size_t)bid * Ll + tid + i * 256] = wv;
    wb16[(size_t)bid * Ll + tid + i * 256] = f2bf(wv);
  }
  if (tid == 0) hasany[bid] = any;
}

// ---------------------------------------------------------------------------
// K5: bf16 MFMA partial GEMM, atomically accumulated into cctx (zeroed by
// k_front). A from wb16 [c][l] (direct 16B loads); B gathered per-lane from
// hidb [l][h] (8 u16 at stride Hh per frag) — round-3-verified pattern.
// ---------------------------------------------------------------------------
__global__ __launch_bounds__(256) void k5_mfma(
    const ushort* __restrict__ wb16, const ushort* __restrict__ hidb,
    float* __restrict__ cctx) {
  const int b = blockIdx.x, nt = blockIdx.y, kz = blockIdx.z;  // kz 0..15
  const int tid = threadIdx.x;
  const int w = tid >> 6, lane = tid & 63;
  const int lc = lane & 15, lq = lane >> 4;
  const int h0 = nt * 128 + w * 32;

  f32x4 acc[4][2];
#pragma unroll
  for (int mi = 0; mi < 4; ++mi)
#pragma unroll
    for (int ni = 0; ni < 2; ++ni) acc[mi][ni] = (f32x4){0.f, 0.f, 0.f, 0.f};

  const ushort* Abase =
      wb16 + (size_t)b * Cc * Ll + (size_t)lc * Ll + kz * 256 + lq * 8;
  const ushort* Bbase =
      hidb + ((size_t)(b * Ll + kz * 256 + lq * 8)) * Hh + h0 + lc;

#pragma unroll 2
  for (int kb = 0; kb < 8; ++kb) {
    s16x8 af[4];
#pragma unroll
    for (int mi = 0; mi < 4; ++mi)
      af[mi] = *(const s16x8*)(Abase + (size_t)mi * 16 * Ll + kb * 32);
    s16x8 bfv[2];
#pragma unroll
    for (int ni = 0; ni < 2; ++ni) {
      const ushort* bp = Bbase + (size_t)kb * 32 * Hh + ni * 16;
      s16x8 t;
#pragma unroll
      for (int j = 0; j < 8; ++j) t[j] = (short)bp[(size_t)j * Hh];
      bfv[ni] = t;
    }
#pragma unroll
    for (int mi = 0; mi < 4; ++mi)
#pragma unroll
      for (int ni = 0; ni < 2; ++ni)
        acc[mi][ni] = __builtin_amdgcn_mfma_f32_16x16x32_bf16(
            af[mi], bfv[ni], acc[mi][ni], 0, 0, 0);
  }

#pragma unroll
  for (int mi = 0; mi < 4; ++mi)
#pragma unroll
    for (int ni = 0; ni < 2; ++ni)
#pragma unroll
      for (int r = 0; r < 4; ++r)
        atomicAdd(&cctx[((size_t)(b * Cc + mi * 16 + lq * 4 + r)) * Hh + h0 +
                        ni * 16 + lc],
                  acc[mi][ni][r]);
}

// ---------------------------------------------------------------------------
// K7: attended = mask ? (mix @ cctx) * gate : hidden
// LDS-resident outer product; fallback (!hasany) patched into the LDS copy.
// ---------------------------------------------------------------------------
__global__ __launch_bounds__(256) void k7_out(
    const float* __restrict__ hid, const float* __restrict__ act,
    const float* __restrict__ dinv, const float* __restrict__ cctx,
    const int* __restrict__ hasany, const int* __restrict__ mask,
    const int* __restrict__ cnt, const int* __restrict__ cmax,
    float* __restrict__ out) {
  __shared__ float cct[64][128];   // [c][h] 32 KB
  __shared__ float mixs[64][64];   // [tok][c] 16 KB
  __shared__ float gateb[64];
  __shared__ int maskb[64];
  const int b = blockIdx.x;
  const int l0 = blockIdx.y * 64;
  const int h0 = blockIdx.z * 128;
  const int tid = threadIdx.x;
  const int w = tid >> 6;

  {
    const float* g = cctx + (size_t)(b * Cc + (tid >> 5)) * Hh + h0 + (tid & 31) * 4;
    float* lb = &cct[0][0] + (2 * w) * 128;
#pragma unroll
    for (int i = 0; i < 8; ++i)
      gl16(g + (size_t)(i * 8) * Hh, lb + i * 8 * 128);
  }
#pragma unroll
  for (int i = 0; i < 4; ++i) {
    int e = tid + i * 256;
    int t = e >> 4, c4 = (e & 15) * 4;
    float4 a4 = *(const float4*)(act + ((size_t)(b * Ll + l0 + t)) * Cc + c4);
    float dv = dinv[b * Ll + l0 + t];
    a4.x = fmaxf(a4.x, 0.f) * dv;
    a4.y = fmaxf(a4.y, 0.f) * dv;
    a4.z = fmaxf(a4.z, 0.f) * dv;
    a4.w = fmaxf(a4.w, 0.f) * dv;
    *(float4*)&mixs[t][c4] = a4;
  }
  if (tid < 64) {
    int l = l0 + tid;
    maskb[tid] = mask[b * Ll + l];
    gateb[tid] = 1.0f + (float)cnt[b * Ll + l] / fmaxf((float)cmax[b], 1.0f);
  }
  __syncthreads();

  // fallback patch: rows with no active channel get hid[b][L-1][h]
  {
    int c = tid >> 2, hq = (tid & 3) * 32;
    if (!hasany[b * Cc + c]) {
      const float* hl = hid + ((size_t)(b * Ll + Ll - 1)) * Hh + h0 + hq;
#pragma unroll 8
      for (int j = 0; j < 32; ++j) cct[c][hq + j] = hl[j];
    }
  }
  __syncthreads();

  const int hcol = (tid & 31) * 4;
  const int tok0 = (tid >> 5) * 8;

  f32x4 acc[8];
#pragma unroll
  for (int t = 0; t < 8; ++t) acc[t] = (f32x4){0.f, 0.f, 0.f, 0.f};

#pragma unroll 4
  for (int c0 = 0; c0 < 64; c0 += 4) {
    f32x4 cv0 = *(const f32x4*)&cct[c0 + 0][hcol];
    f32x4 cv1 = *(const f32x4*)&cct[c0 + 1][hcol];
    f32x4 cv2 = *(const f32x4*)&cct[c0 + 2][hcol];
    f32x4 cv3 = *(const f32x4*)&cct[c0 + 3][hcol];
#pragma unroll
    for (int t = 0; t < 8; ++t) {
      f32x4 mv = *(const f32x4*)&mixs[tok0 + t][c0];
      f32x4 a = acc[t];
      a = cv0 * mv.x + a;
      a = cv1 * mv.y + a;
      a = cv2 * mv.z + a;
      a = cv3 * mv.w + a;
      acc[t] = a;
    }
  }

#pragma unroll
  for (int t = 0; t < 8; ++t) {
    int tok = tok0 + t;
    size_t off = ((size_t)(b * Ll + l0 + tok)) * Hh + h0 + hcol;
    f32x4 o;
    if (maskb[tok]) {
      o = acc[t] * gateb[tok];
    } else {
      o = *(const f32x4*)(hid + off);
    }
    *(f32x4*)(out + off) = o;
  }
}

// ---------------------------------------------------------------------------
extern "C" void kernel_launch(void* const* d_in, const int* in_sizes, int n_in,
                              void* d_out, int out_size, void* d_ws,
                              size_t ws_size, hipStream_t stream) {
  const float* hid = (const float*)d_in[0];
  const int* mask = (const int*)d_in[1];
  const int* cnt = (const int*)d_in[2];
  const float* act = (const float*)d_in[3];
  const float* pw = (const float*)d_in[4];
  const float* pb = (const float*)d_in[5];
  const float* sw = (const float*)d_in[6];
  const float* sb = (const float*)d_in[7];

  float* out_att = (float*)d_out;                 // (B,L,H)
  float* out_w = out_att + (size_t)Bb * Ll * Hh;  // (B,C,L)

  float* ws = (float*)d_ws;
  float* cctx = ws;                               // 262144 f
  int* cmaxi = (int*)(ws + 262144);               // 8 i
  float* logits = ws + 262152;                    // 32768 f
  float* actT = ws + 294920;                      // 2097152 f
  float* dinv = ws + 2392072;                     // 32768 f
  int* hasany = (int*)(ws + 2424840);             // 512 i
  ushort* pwT = (ushort*)(ws + 2425352);          // 262144 bf16
  ushort* wb16 = (ushort*)(ws + 2556424);         // 2097152 bf16

  // bf16 copy of hid lives in the (not-yet-written) out_att region:
  //   hidb = floats [0 .. 8388608)  (33.5 MB, [l][h] row-major)
  // k0/k5 consume it; k7_out overwrites all of out_att at the very end.
  ushort* hidb = (ushort*)out_att;

  // 5 dispatches total.
  k_front<<<2824, 256, 0, stream>>>(hid, cnt, sb, pw, act, hidb, logits, pwT,
                                    cmaxi, actT, dinv, cctx);
  k0_gemm<<<dim3(256, 4), 256, 0, stream>>>(hidb, pwT, pb, sw, logits);
  k3_softmax<<<512, 256, 0, stream>>>(actT, logits, out_w, wb16, hasany);
  k5_mfma<<<dim3(8, 4, 16), 256, 0, stream>>>(wb16, hidb, cctx);
  k7_out<<<dim3(8, 64, 4), 256, 0, stream>>>(hid, act, dinv, cctx, hasany,
                                             mask, cnt, cmaxi, out_att);
}